// Round 17
// baseline (199.814 us; speedup 1.0000x reference)
//
#include <hip/hip_runtime.h>
#include <math.h>

#define A_N      5
#define GRID_HW  52
#define NCLS     80
#define CH       85
#define SCORE_T  0.15f
#define IOU_T    0.5f
#define NEGV     (-1e9f)
#define MAXOUT   10

#define WAVES_PB     4                  // waves per decode block
#define BPW          32                 // boxes per wave
#define WAVE_FLOATS  (BPW * CH)         // 2720 floats = 10,880 B per wave
#define WAVE_FULL    10                 // 10 x 64 lanes x 16 B = 640 float4
#define WAVE_TAIL    40                 // +40 float4 = 680 = 2720 floats

#define RANK_BLOCKS  32
#define RANK_THREADS 256
#define RCAP         2048               // walk capacity (M measured ~1500)
#define SLOTS        32                 // RCAP / 64 register slots per lane

// fast exp: v_exp_f32 (~1e-7 rel err). Argmax uses raw logits (exact); score
// values have 1.54 tolerance; proven across rounds 4-16 (absmax 0).
__device__ __forceinline__ float fexp(float x) { return __expf(x); }

// async global->LDS, 16B/lane. LDS dest = wave-uniform base + lane*16.
__device__ __forceinline__ void gload_lds16(const float* g, float* l) {
    __builtin_amdgcn_global_load_lds(
        (const __attribute__((address_space(1))) unsigned int*)g,
        (__attribute__((address_space(3))) unsigned int*)l, 16, 0, 0);
}

__global__ void init_counters_kernel(int* __restrict__ counters) {
    counters[0] = 0;   // compacted-slot counter
    counters[1] = 0;   // rank-kernel finished-block ticket
}

// ---------------------------------------------------------------------------
// Decode (structure unchanged; now also records the ORIGINAL box index pgi
// for exact jnp.argmax tie-break semantics in the rank pass).
// ---------------------------------------------------------------------------
__global__ __launch_bounds__(256) void decode_kernel(
    const float* __restrict__ preds,
    const float* __restrict__ anchors,
    float4* __restrict__ pbox, float* __restrict__ pscore,
    float* __restrict__ pcls, int* __restrict__ pgi,
    int* __restrict__ counter, int N, int capacity)
{
    __shared__ __align__(16) float lds[WAVES_PB * WAVE_FLOATS];

    const int lane = (int)threadIdx.x & 63;
    const int wid  = (int)threadIdx.x >> 6;
    const int wt   = blockIdx.x * WAVES_PB + wid;   // wave-tile (32 boxes)
    if (wt * BPW >= N) return;                      // whole-wave guard

    const float* gbase = preds + (size_t)wt * WAVE_FLOATS;
    float* lbase = lds + wid * WAVE_FLOATS;

#pragma unroll
    for (int i = 0; i < WAVE_FULL; ++i)
        gload_lds16(gbase + (size_t)(i * 64 + lane) * 4, lbase + i * 256);
    if (lane < WAVE_TAIL)
        gload_lds16(gbase + (size_t)(WAVE_FULL * 64 + lane) * 4,
                    lbase + WAVE_FULL * 256);

    asm volatile("s_waitcnt vmcnt(0)" ::: "memory");
    __builtin_amdgcn_sched_barrier(0);

    const int b  = lane >> 1;            // box within wave segment (0..31)
    const int h  = lane & 1;             // half of the 80 classes
    const int gi = wt * BPW + b;
    const float* bp = lbase + b * CH;
    const float* cl = bp + 5 + h * 40;

    float s = 0.0f;
    float m = -INFINITY;
    int   am = h * 40;
#pragma unroll
    for (int j = 0; j < 40; ++j) {
        float x = cl[j];
        s += fexp(x);
        if (x > m) { m = x; am = h * 40 + j; }
    }
    {
        float m2 = __shfl_xor(m, 1);
        float s2 = __shfl_xor(s, 1);
        int   am2 = __shfl_xor(am, 1);
        s += s2;
        if (m2 > m || (m2 == m && am2 < am)) { m = m2; am = am2; }
    }

    float conf  = 1.0f / (1.0f + fexp(-bp[4]));
    float score = conf * fexp(m) / s;

    bool live = (h == 0) && (gi < N) && (score >= SCORE_T);

    unsigned long long mask = __ballot(live);
    if (mask) {
        int nlive  = __popcll(mask);
        int leader = (int)__ffsll((long long)mask) - 1;
        int base_ = 0;
        if (lane == leader) base_ = atomicAdd(counter, nlive);
        base_ = __shfl(base_, leader);
        if (live) {
            int a = gi % A_N;
            int t = gi / A_N;
            int wx = t % GRID_HW;
            int hy = (t / GRID_HW) % GRID_HW;
            const float inv = 1.0f / (float)GRID_HW;
            float cx = (1.0f / (1.0f + fexp(-bp[0])) + (float)wx) * inv;
            float cy = (1.0f / (1.0f + fexp(-bp[1])) + (float)hy) * inv;
            float bw = fexp(bp[2]) * anchors[2 * a]     * inv;
            float bh = fexp(bp[3]) * anchors[2 * a + 1] * inv;

            int pos = base_ + __popcll(mask & ((1ull << lane) - 1));
            if (pos < capacity) {
                pbox[pos]   = make_float4(cy - 0.5f * bh, cx - 0.5f * bw,
                                          cy + 0.5f * bh, cx + 0.5f * bw);
                pscore[pos] = score;
                pcls[pos]   = (float)am;
                pgi[pos]    = gi;
            }
        }
    }
}

// ---------------------------------------------------------------------------
// Rank + scatter + last-block walk. Replaces the 10 serial grid-reduction
// rounds (the measured ~3us/round floor) with:
//   (a) parallel rank: rank_i = #{j: s_j>s_i or (s_j==s_i && gi_j<gi_i)}
//       (M^2 compares, spread over 8192 threads, scores L2-broadcast),
//       scatter into sorted arrays — a perfect permutation;
//   (b) LAST BLOCK (ticket+fence): one wave walks ranks ascending with all
//       sorted boxes in registers (32 slots/lane) — greedy NMS == sorted
//       walk keeping boxes not suppressed by previously kept ones.
//       Zero barriers, zero butterflies, ~600cy per emission.
// ---------------------------------------------------------------------------
__global__ __launch_bounds__(RANK_THREADS, 1) void ranknms_kernel(
    const float4* __restrict__ pbox, const float* __restrict__ pscore,
    const float* __restrict__ pcls, const int* __restrict__ pgi,
    int* counters, int capacity,
    float4* __restrict__ sbox, float* __restrict__ ssc,
    float* __restrict__ scls, float* __restrict__ pscratch,
    float* __restrict__ out)
{
    __shared__ float l_y0[RCAP], l_x0[RCAP], l_y1[RCAP], l_x1[RCAP];
    __shared__ float l_sc[RCAP], l_cl[RCAP];
    __shared__ float orow[MAXOUT * 6];
    __shared__ float psc[4];
    __shared__ int   pix[4];
    __shared__ int   lastFlag;

    const int tid = (int)threadIdx.x;
    const int gid = (int)blockIdx.x * RANK_THREADS + tid;

    int M = counters[0];
    if (M > capacity) M = capacity;

    // ---------------- phase A: rank + scatter (all blocks) ----------------
    if (M <= RCAP && gid < M) {
        float si = pscore[gid];
        int   gii = pgi[gid];
        int rank = 0;
        int j = 0;
        for (; j + 4 <= M; j += 4) {
            float4 s4 = *reinterpret_cast<const float4*>(pscore + j);
            int4   g4 = *reinterpret_cast<const int4*>(pgi + j);
            rank += (s4.x > si) || (s4.x == si && g4.x < gii);
            rank += (s4.y > si) || (s4.y == si && g4.y < gii);
            rank += (s4.z > si) || (s4.z == si && g4.z < gii);
            rank += (s4.w > si) || (s4.w == si && g4.w < gii);
        }
        for (; j < M; ++j) {
            float sj = pscore[j];
            rank += (sj > si) || (sj == si && pgi[j] < gii);
        }
        sbox[rank] = pbox[gid];
        ssc[rank]  = si;
        scls[rank] = pcls[gid];
    }

    // ---------------- ticket: last block proceeds -------------------------
    __syncthreads();
    if (tid == 0) {
        __threadfence();                       // publish sorted arrays
        int prev = atomicAdd(counters + 1, 1);
        lastFlag = (prev == (int)gridDim.x - 1);
    }
    __syncthreads();
    if (!lastFlag) return;
    __threadfence();                           // acquire all blocks' scatter

    // ---------------- phase B: walk (last block) --------------------------
    if (M <= RCAP) {
        // stage sorted arrays into LDS (uniform winner lookups)
        for (int r = tid; r < M; r += RANK_THREADS) {
            float4 b = sbox[r];
            l_y0[r] = b.x; l_x0[r] = b.y; l_y1[r] = b.z; l_x1[r] = b.w;
            l_sc[r] = ssc[r]; l_cl[r] = scls[r];
        }
        __syncthreads();

        if (tid < 64) {                        // wave 0 walks alone
            const int lane = tid;
            float by0[SLOTS], bx0[SLOTS], by1[SLOTS], bx1[SLOTS];
            unsigned alive = 0u;
#pragma unroll
            for (int s = 0; s < SLOTS; ++s) {
                int r = s * 64 + lane;
                if (r < M) {
                    by0[s] = l_y0[r]; bx0[s] = l_x0[r];
                    by1[s] = l_y1[r]; bx1[s] = l_x1[r];
                    alive |= (1u << s);
                } else {
                    by0[s] = 0.f; bx0[s] = 0.f; by1[s] = 0.f; bx1[s] = 0.f;
                }
            }

            for (int it = 0; it < MAXOUT; ++it) {
                // lowest alive rank: <=32 uniform ballots (usually 1)
                int r = -1;
                for (int s = 0; s < SLOTS; ++s) {
                    unsigned long long mk = __ballot((alive >> s) & 1u);
                    if (mk) { r = s * 64 + (int)__ffsll((long long)mk) - 1; break; }
                }

                if (r >= 0) {
                    float wy0 = l_y0[r], wx0 = l_x0[r];
                    float wy1 = l_y1[r], wx1 = l_x1[r];
                    if (lane == 0) {
                        orow[it*6+0] = wy0; orow[it*6+1] = wx0;
                        orow[it*6+2] = wy1; orow[it*6+3] = wx1;
                        orow[it*6+4] = l_sc[r]; orow[it*6+5] = l_cl[r];
                    }
                    // explicit winner kill (self-IoU of zero-area boxes is 0)
                    if (lane == (r & 63)) alive &= ~(1u << (r >> 6));

                    float a1 = fmaxf(wy1 - wy0, 0.f) * fmaxf(wx1 - wx0, 0.f);
#pragma unroll
                    for (int s = 0; s < SLOTS; ++s) {
                        float ty = fmaxf(wy0, by0[s]);
                        float tx = fmaxf(wx0, bx0[s]);
                        float by = fminf(wy1, by1[s]);
                        float bx = fminf(wx1, bx1[s]);
                        float inter = fmaxf(by - ty, 0.f) * fmaxf(bx - tx, 0.f);
                        float a2 = fmaxf(by1[s] - by0[s], 0.f)
                                 * fmaxf(bx1[s] - bx0[s], 0.f);
                        float iou = inter / (a1 + a2 - inter + 1e-9f);
                        if (iou > IOU_T) alive &= ~(1u << s);
                    }
                } else if (lane == 0) {
                    orow[it*6+0] = 0.f; orow[it*6+1] = 0.f; orow[it*6+2] = 0.f;
                    orow[it*6+3] = 0.f; orow[it*6+4] = 0.f; orow[it*6+5] = 0.f;
                }
            }
        }
        __syncthreads();
    } else {
        // ------- fallback (M > RCAP, never hit: M~1500): iterative, 4 waves
        const int lane = tid & 63;
        const int wid  = tid >> 6;
        for (int j = tid; j < M; j += RANK_THREADS) pscratch[j] = pscore[j];
        __syncthreads();

        for (int it = 0; it < MAXOUT; ++it) {
            float bs = -INFINITY; int bi = -1;
            for (int j = tid; j < M; j += RANK_THREADS) {
                float v = pscratch[j];
                if (v > bs) { bs = v; bi = j; }
            }
#pragma unroll
            for (int off = 32; off; off >>= 1) {
                float os = __shfl_xor(bs, off);
                int   oi = __shfl_xor(bi, off);
                if (os > bs || (os == bs && oi != -1 && (bi == -1 || oi < bi))) {
                    bs = os; bi = oi;
                }
            }
            if (lane == 0) { psc[wid] = bs; pix[wid] = bi; }
            __syncthreads();
            bs = psc[0]; bi = pix[0];
#pragma unroll
            for (int w = 1; w < 4; ++w) {
                float os = psc[w]; int oi = pix[w];
                if (os > bs || (os == bs && oi != -1 && (bi == -1 || oi < bi))) {
                    bs = os; bi = oi;
                }
            }
            bool valid = (bi >= 0) && (bs > NEGV * 0.5f);
            float4 wb = make_float4(0.f, 0.f, 0.f, 0.f);
            if (valid) wb = pbox[bi];
            if (tid == 0) {
                if (valid) {
                    orow[it*6+0] = wb.x; orow[it*6+1] = wb.y;
                    orow[it*6+2] = wb.z; orow[it*6+3] = wb.w;
                    orow[it*6+4] = bs;   orow[it*6+5] = pcls[bi];
                    pscratch[bi] = NEGV;
                } else {
                    orow[it*6+0] = 0.f; orow[it*6+1] = 0.f; orow[it*6+2] = 0.f;
                    orow[it*6+3] = 0.f; orow[it*6+4] = 0.f; orow[it*6+5] = 0.f;
                }
            }
            __syncthreads();
            if (valid) {
                float a1 = fmaxf(wb.z - wb.x, 0.f) * fmaxf(wb.w - wb.y, 0.f);
                for (int j = tid; j < M; j += RANK_THREADS) {
                    float4 bj = pbox[j];
                    float ty = fmaxf(wb.x, bj.x);
                    float tx = fmaxf(wb.y, bj.y);
                    float by = fminf(wb.z, bj.z);
                    float bx = fminf(wb.w, bj.w);
                    float inter = fmaxf(by - ty, 0.f) * fmaxf(bx - tx, 0.f);
                    float a2 = fmaxf(bj.z - bj.x, 0.f) * fmaxf(bj.w - bj.y, 0.f);
                    float iou = inter / (a1 + a2 - inter + 1e-9f);
                    if (iou > IOU_T) pscratch[j] = NEGV;
                }
            }
            __syncthreads();
        }
    }

    if (tid < MAXOUT * 6) out[tid] = orow[tid];   // single coalesced write
}

extern "C" void kernel_launch(void* const* d_in, const int* in_sizes, int n_in,
                              void* d_out, int out_size, void* d_ws, size_t ws_size,
                              hipStream_t stream) {
    (void)n_in; (void)out_size;
    const float* preds   = (const float*)d_in[0];
    const float* anchors = (const float*)d_in[1];
    float* out = (float*)d_out;

    int N = in_sizes[0] / CH;   // 216,320 boxes

    // Workspace: [0,64) counters; pbox f4[cap]; sbox f4[cap]; then scalar
    // arrays pscore, pcls, pgi, pscratch, ssc, scls (cap each, 16B-aligned
    // because cap is rounded to a multiple of 4). 56 B per slot.
    char* ws = (char*)d_ws;
    int* counters = (int*)ws;
    size_t avail = (ws_size > 64) ? (ws_size - 64) : 0;
    long long cap = (long long)(avail / 56);
    if (cap > N) cap = N;
    if (cap < 0) cap = 0;
    cap &= ~3LL;                       // multiple of 4 -> 16B-aligned arrays
    int capacity = (int)cap;

    float4* pbox    = (float4*)(ws + 64);
    float4* sbox    = pbox + capacity;
    float*  pscore  = (float*)(sbox + capacity);
    float*  pcls    = pscore + capacity;
    int*    pgi     = (int*)(pcls + capacity);
    float*  pscratch= (float*)(pgi + capacity);
    float*  ssc     = pscratch + capacity;
    float*  scls    = ssc + capacity;

    init_counters_kernel<<<1, 1, 0, stream>>>(counters);

    int nBlocks = (N + WAVES_PB * BPW - 1) / (WAVES_PB * BPW);   // 1690
    decode_kernel<<<nBlocks, 256, 0, stream>>>(
        preds, anchors, pbox, pscore, pcls, pgi, counters, N, capacity);
    ranknms_kernel<<<RANK_BLOCKS, RANK_THREADS, 0, stream>>>(
        pbox, pscore, pcls, pgi, counters, capacity,
        sbox, ssc, scls, pscratch, out);
}

// Round 18
// 180.471 us; speedup vs baseline: 1.1072x; 1.1072x over previous
//
#include <hip/hip_runtime.h>
#include <math.h>

#define A_N      5
#define GRID_HW  52
#define NCLS     80
#define CH       85
#define SCORE_T  0.15f
#define IOU_T    0.5f
#define NEGV     (-1e9f)
#define MAXOUT   10

#define WAVES_PB     4                  // waves per decode block
#define BPW          32                 // boxes per wave
#define WAVE_FLOATS  (BPW * CH)         // 2720 floats = 10,880 B per wave
#define WAVE_FULL    10                 // 10 x 64 lanes x 16 B = 640 float4
#define WAVE_TAIL    40                 // +40 float4 = 680 = 2720 floats

#define RANK_BLOCKS  32
#define RANK_THREADS 256
#define RANK_STRIDE  (RANK_BLOCKS * RANK_THREADS)

// fast exp: v_exp_f32 (~1e-7 rel err). Argmax uses raw logits (exact); score
// values have 1.54 tolerance; proven across rounds 4-17 (absmax 0).
__device__ __forceinline__ float fexp(float x) { return __expf(x); }

// async global->LDS, 16B/lane. LDS dest = wave-uniform base + lane*16.
__device__ __forceinline__ void gload_lds16(const float* g, float* l) {
    __builtin_amdgcn_global_load_lds(
        (const __attribute__((address_space(1))) unsigned int*)g,
        (__attribute__((address_space(3))) unsigned int*)l, 16, 0, 0);
}

__global__ void init_counters_kernel(int* __restrict__ counters) {
    counters[0] = 0;   // compacted-slot counter
    counters[1] = 0;   // rank-kernel finished-block ticket
}

// ---------------------------------------------------------------------------
// Decode (unchanged): 4 independent waves/block, wave-local global_load_lds
// staging + vmcnt drain, 2 lanes/box one-pass softmax, ballot compaction.
// Also records original box index pgi for exact argmax tie-break.
// ---------------------------------------------------------------------------
__global__ __launch_bounds__(256) void decode_kernel(
    const float* __restrict__ preds,
    const float* __restrict__ anchors,
    float4* __restrict__ pbox, float* __restrict__ pscore,
    float* __restrict__ pcls, int* __restrict__ pgi,
    int* __restrict__ counter, int N, int capacity)
{
    __shared__ __align__(16) float lds[WAVES_PB * WAVE_FLOATS];

    const int lane = (int)threadIdx.x & 63;
    const int wid  = (int)threadIdx.x >> 6;
    const int wt   = blockIdx.x * WAVES_PB + wid;   // wave-tile (32 boxes)
    if (wt * BPW >= N) return;                      // whole-wave guard

    const float* gbase = preds + (size_t)wt * WAVE_FLOATS;
    float* lbase = lds + wid * WAVE_FLOATS;

#pragma unroll
    for (int i = 0; i < WAVE_FULL; ++i)
        gload_lds16(gbase + (size_t)(i * 64 + lane) * 4, lbase + i * 256);
    if (lane < WAVE_TAIL)
        gload_lds16(gbase + (size_t)(WAVE_FULL * 64 + lane) * 4,
                    lbase + WAVE_FULL * 256);

    asm volatile("s_waitcnt vmcnt(0)" ::: "memory");
    __builtin_amdgcn_sched_barrier(0);

    const int b  = lane >> 1;            // box within wave segment (0..31)
    const int h  = lane & 1;             // half of the 80 classes
    const int gi = wt * BPW + b;
    const float* bp = lbase + b * CH;
    const float* cl = bp + 5 + h * 40;

    float s = 0.0f;
    float m = -INFINITY;
    int   am = h * 40;
#pragma unroll
    for (int j = 0; j < 40; ++j) {
        float x = cl[j];
        s += fexp(x);
        if (x > m) { m = x; am = h * 40 + j; }
    }
    {
        float m2 = __shfl_xor(m, 1);
        float s2 = __shfl_xor(s, 1);
        int   am2 = __shfl_xor(am, 1);
        s += s2;
        if (m2 > m || (m2 == m && am2 < am)) { m = m2; am = am2; }
    }

    float conf  = 1.0f / (1.0f + fexp(-bp[4]));
    float score = conf * fexp(m) / s;

    bool live = (h == 0) && (gi < N) && (score >= SCORE_T);

    unsigned long long mask = __ballot(live);
    if (mask) {
        int nlive  = __popcll(mask);
        int leader = (int)__ffsll((long long)mask) - 1;
        int base_ = 0;
        if (lane == leader) base_ = atomicAdd(counter, nlive);
        base_ = __shfl(base_, leader);
        if (live) {
            int a = gi % A_N;
            int t = gi / A_N;
            int wx = t % GRID_HW;
            int hy = (t / GRID_HW) % GRID_HW;
            const float inv = 1.0f / (float)GRID_HW;
            float cx = (1.0f / (1.0f + fexp(-bp[0])) + (float)wx) * inv;
            float cy = (1.0f / (1.0f + fexp(-bp[1])) + (float)hy) * inv;
            float bw = fexp(bp[2]) * anchors[2 * a]     * inv;
            float bh = fexp(bp[3]) * anchors[2 * a + 1] * inv;

            int pos = base_ + __popcll(mask & ((1ull << lane) - 1));
            if (pos < capacity) {
                pbox[pos]   = make_float4(cy - 0.5f * bh, cx - 0.5f * bw,
                                          cy + 0.5f * bh, cx + 0.5f * bw);
                pscore[pos] = score;
                pcls[pos]   = (float)am;
                pgi[pos]    = gi;
            }
        }
    }
}

// ---------------------------------------------------------------------------
// Rank + scatter + last-block batched walk.
// Phase A (all blocks, grid-stride): rank_i = #{j: s_j>s_i or (s_j==s_i &&
//   gi_j<gi_i)} — a perfect permutation (gi unique); scatter box/score/class
//   into sorted arrays. Descending (score, gi-asc) order == the order greedy
//   argmax would select; ties match jnp.argmax (first original index).
// Phase B (last block via ticket+fence, ONE wave): walk sorted candidates in
//   batches of 64. Each lane tests its candidate against the <=10 kept boxes
//   (static-unrolled, register kept-list — no spill), then keeps are
//   serialized within the batch by ballot/ffs + shuffle broadcast. A
//   candidate is kept iff IoU <= 0.5 vs ALL previously kept (== greedy NMS).
//   Stops at 10 kept; expected 1-2 batches on random boxes. ~60 VGPR.
// ---------------------------------------------------------------------------
__global__ __launch_bounds__(RANK_THREADS) void ranknms_kernel(
    const float4* __restrict__ pbox, const float* __restrict__ pscore,
    const float* __restrict__ pcls, const int* __restrict__ pgi,
    int* counters, int capacity,
    float4* __restrict__ sbox, float* __restrict__ ssc,
    float* __restrict__ scls, float* __restrict__ out)
{
    __shared__ float orow[MAXOUT * 6];
    __shared__ int   lastFlag;

    const int tid = (int)threadIdx.x;
    const int gid = (int)blockIdx.x * RANK_THREADS + tid;

    int M = counters[0];
    if (M > capacity) M = capacity;

    // ---------------- phase A: rank + scatter (grid-stride) ---------------
    for (int i = gid; i < M; i += RANK_STRIDE) {
        float si  = pscore[i];
        int   gii = pgi[i];
        int rank = 0;
        int j = 0;
        for (; j + 4 <= M; j += 4) {
            float4 s4 = *reinterpret_cast<const float4*>(pscore + j);
            int4   g4 = *reinterpret_cast<const int4*>(pgi + j);
            rank += (s4.x > si) || (s4.x == si && g4.x < gii);
            rank += (s4.y > si) || (s4.y == si && g4.y < gii);
            rank += (s4.z > si) || (s4.z == si && g4.z < gii);
            rank += (s4.w > si) || (s4.w == si && g4.w < gii);
        }
        for (; j < M; ++j) {
            float sj = pscore[j];
            rank += (sj > si) || (sj == si && pgi[j] < gii);
        }
        sbox[rank] = pbox[i];
        ssc[rank]  = si;
        scls[rank] = pcls[i];
    }

    // ---------------- ticket: last block proceeds -------------------------
    __syncthreads();
    if (tid == 0) {
        __threadfence();                       // publish sorted arrays
        int prev = atomicAdd(counters + 1, 1);
        lastFlag = (prev == (int)gridDim.x - 1);
    }
    __syncthreads();
    if (!lastFlag) return;
    __threadfence();                           // acquire all blocks' scatter

    // ---------------- phase B: batched walk (one wave) --------------------
    if (tid < 64) {
        const int lane = tid;
        float4 kb[MAXOUT];                     // kept boxes (wave-uniform)
        int kept = 0;

        for (int r0 = 0; r0 < M && kept < MAXOUT; r0 += 64) {
            int r = r0 + lane;
            bool in = (r < M);
            float4 cb  = in ? sbox[r]  : make_float4(0.f, 0.f, 0.f, 0.f);
            float  csc = in ? ssc[r]   : 0.f;
            float  ccl = in ? scls[r]  : 0.f;
            float  ca  = fmaxf(cb.z - cb.x, 0.f) * fmaxf(cb.w - cb.y, 0.f);
            bool alive = in;

            // test vs kept-so-far (static indices; predicated on k<kept)
#pragma unroll
            for (int k = 0; k < MAXOUT; ++k) {
                if (k < kept && alive) {
                    float ka = fmaxf(kb[k].z - kb[k].x, 0.f)
                             * fmaxf(kb[k].w - kb[k].y, 0.f);
                    float ty = fmaxf(kb[k].x, cb.x);
                    float tx = fmaxf(kb[k].y, cb.y);
                    float by = fminf(kb[k].z, cb.z);
                    float bx = fminf(kb[k].w, cb.w);
                    float inter = fmaxf(by - ty, 0.f) * fmaxf(bx - tx, 0.f);
                    float iou = inter / (ka + ca - inter + 1e-9f);
                    if (iou > IOU_T) alive = false;
                }
            }

            // serialize keeps within the batch
            unsigned long long am = __ballot(alive);
            while (am && kept < MAXOUT) {
                int w = (int)__ffsll((long long)am) - 1;   // lowest rank
                float wy0 = __shfl(cb.x, w), wx0 = __shfl(cb.y, w);
                float wy1 = __shfl(cb.z, w), wx1 = __shfl(cb.w, w);
                float wsc = __shfl(csc, w),  wcl = __shfl(ccl, w);

                if (lane == 0) {
                    orow[kept*6+0] = wy0; orow[kept*6+1] = wx0;
                    orow[kept*6+2] = wy1; orow[kept*6+3] = wx1;
                    orow[kept*6+4] = wsc; orow[kept*6+5] = wcl;
                }
#pragma unroll
                for (int k = 0; k < MAXOUT; ++k)   // kb[kept] via static idx
                    if (k == kept) kb[k] = make_float4(wy0, wx0, wy1, wx1);
                kept++;

                if (lane == w) alive = false;      // consumed
                if (alive) {                        // suppress vs new keep
                    float wa = fmaxf(wy1 - wy0, 0.f) * fmaxf(wx1 - wx0, 0.f);
                    float ty = fmaxf(wy0, cb.x);
                    float tx = fmaxf(wx0, cb.y);
                    float by = fminf(wy1, cb.z);
                    float bx = fminf(wx1, cb.w);
                    float inter = fmaxf(by - ty, 0.f) * fmaxf(bx - tx, 0.f);
                    float iou = inter / (wa + ca - inter + 1e-9f);
                    if (iou > IOU_T) alive = false;
                }
                am = __ballot(alive);
            }
        }

        if (lane == 0) {
            for (int it = kept; it < MAXOUT; ++it) {
                orow[it*6+0] = 0.f; orow[it*6+1] = 0.f; orow[it*6+2] = 0.f;
                orow[it*6+3] = 0.f; orow[it*6+4] = 0.f; orow[it*6+5] = 0.f;
            }
        }
    }

    __syncthreads();
    if (tid < MAXOUT * 6) out[tid] = orow[tid];   // single coalesced write
}

extern "C" void kernel_launch(void* const* d_in, const int* in_sizes, int n_in,
                              void* d_out, int out_size, void* d_ws, size_t ws_size,
                              hipStream_t stream) {
    (void)n_in; (void)out_size;
    const float* preds   = (const float*)d_in[0];
    const float* anchors = (const float*)d_in[1];
    float* out = (float*)d_out;

    int N = in_sizes[0] / CH;   // 216,320 boxes

    // Workspace: [0,64) counters; pbox f4[cap]; sbox f4[cap]; pscore, pcls,
    // ssc, scls (float[cap]); pgi (int[cap]). 52 B per slot, cap multiple
    // of 4 so every array stays 16B-aligned.
    char* ws = (char*)d_ws;
    int* counters = (int*)ws;
    size_t avail = (ws_size > 64) ? (ws_size - 64) : 0;
    long long cap = (long long)(avail / 52);
    if (cap > N) cap = N;
    if (cap < 0) cap = 0;
    cap &= ~3LL;
    int capacity = (int)cap;

    float4* pbox   = (float4*)(ws + 64);
    float4* sbox   = pbox + capacity;
    float*  pscore = (float*)(sbox + capacity);
    float*  pcls   = pscore + capacity;
    float*  ssc    = pcls + capacity;
    float*  scls   = ssc + capacity;
    int*    pgi    = (int*)(scls + capacity);

    init_counters_kernel<<<1, 1, 0, stream>>>(counters);

    int nBlocks = (N + WAVES_PB * BPW - 1) / (WAVES_PB * BPW);   // 1690
    decode_kernel<<<nBlocks, 256, 0, stream>>>(
        preds, anchors, pbox, pscore, pcls, pgi, counters, N, capacity);
    ranknms_kernel<<<RANK_BLOCKS, RANK_THREADS, 0, stream>>>(
        pbox, pscore, pcls, pgi, counters, capacity,
        sbox, ssc, scls, out);
}

// Round 19
// 117.383 us; speedup vs baseline: 1.7022x; 1.5375x over previous
//
#include <hip/hip_runtime.h>
#include <math.h>

#define A_N      5
#define GRID_HW  52
#define NCLS     80
#define CH       85
#define SCORE_T  0.15f
#define IOU_T    0.5f
#define NEGV     (-1e9f)
#define MAXOUT   10

#define WAVES_PB     4                  // waves per decode block
#define BPW          32                 // boxes per wave
#define WAVE_FLOATS  (BPW * CH)         // 2720 floats = 10,880 B per wave
#define WAVE_FULL    10                 // 10 x 64 lanes x 16 B = 640 float4
#define WAVE_TAIL    40                 // +40 float4 = 680 = 2720 floats

#define RANK_BLOCKS  8
#define RANK_THREADS 256
#define RANK_STRIDE  (RANK_BLOCKS * RANK_THREADS)   // 2048
#define RANKCAP      4096               // LDS-resident scores+gi (32 KB)

// fast exp: v_exp_f32 (~1e-7 rel err). Argmax uses raw logits (exact); score
// values have 1.54 tolerance; proven across rounds 4-18 (absmax 0).
__device__ __forceinline__ float fexp(float x) { return __expf(x); }

// async global->LDS, 16B/lane. LDS dest = wave-uniform base + lane*16.
__device__ __forceinline__ void gload_lds16(const float* g, float* l) {
    __builtin_amdgcn_global_load_lds(
        (const __attribute__((address_space(1))) unsigned int*)g,
        (__attribute__((address_space(3))) unsigned int*)l, 16, 0, 0);
}

__global__ void init_counters_kernel(int* __restrict__ counters) {
    counters[0] = 0;   // compacted-slot counter
    counters[1] = 0;   // rank-kernel finished-block ticket
}

// ---------------------------------------------------------------------------
// Decode (unchanged): 4 independent waves/block, wave-local global_load_lds
// staging + vmcnt drain, 2 lanes/box one-pass softmax, ballot compaction.
// Records original box index pgi for exact argmax tie-break.
// ---------------------------------------------------------------------------
__global__ __launch_bounds__(256) void decode_kernel(
    const float* __restrict__ preds,
    const float* __restrict__ anchors,
    float4* __restrict__ pbox, float* __restrict__ pscore,
    float* __restrict__ pcls, int* __restrict__ pgi,
    int* __restrict__ counter, int N, int capacity)
{
    __shared__ __align__(16) float lds[WAVES_PB * WAVE_FLOATS];

    const int lane = (int)threadIdx.x & 63;
    const int wid  = (int)threadIdx.x >> 6;
    const int wt   = blockIdx.x * WAVES_PB + wid;   // wave-tile (32 boxes)
    if (wt * BPW >= N) return;                      // whole-wave guard

    const float* gbase = preds + (size_t)wt * WAVE_FLOATS;
    float* lbase = lds + wid * WAVE_FLOATS;

#pragma unroll
    for (int i = 0; i < WAVE_FULL; ++i)
        gload_lds16(gbase + (size_t)(i * 64 + lane) * 4, lbase + i * 256);
    if (lane < WAVE_TAIL)
        gload_lds16(gbase + (size_t)(WAVE_FULL * 64 + lane) * 4,
                    lbase + WAVE_FULL * 256);

    asm volatile("s_waitcnt vmcnt(0)" ::: "memory");
    __builtin_amdgcn_sched_barrier(0);

    const int b  = lane >> 1;            // box within wave segment (0..31)
    const int h  = lane & 1;             // half of the 80 classes
    const int gi = wt * BPW + b;
    const float* bp = lbase + b * CH;
    const float* cl = bp + 5 + h * 40;

    float s = 0.0f;
    float m = -INFINITY;
    int   am = h * 40;
#pragma unroll
    for (int j = 0; j < 40; ++j) {
        float x = cl[j];
        s += fexp(x);
        if (x > m) { m = x; am = h * 40 + j; }
    }
    {
        float m2 = __shfl_xor(m, 1);
        float s2 = __shfl_xor(s, 1);
        int   am2 = __shfl_xor(am, 1);
        s += s2;
        if (m2 > m || (m2 == m && am2 < am)) { m = m2; am = am2; }
    }

    float conf  = 1.0f / (1.0f + fexp(-bp[4]));
    float score = conf * fexp(m) / s;

    bool live = (h == 0) && (gi < N) && (score >= SCORE_T);

    unsigned long long mask = __ballot(live);
    if (mask) {
        int nlive  = __popcll(mask);
        int leader = (int)__ffsll((long long)mask) - 1;
        int base_ = 0;
        if (lane == leader) base_ = atomicAdd(counter, nlive);
        base_ = __shfl(base_, leader);
        if (live) {
            int a = gi % A_N;
            int t = gi / A_N;
            int wx = t % GRID_HW;
            int hy = (t / GRID_HW) % GRID_HW;
            const float inv = 1.0f / (float)GRID_HW;
            float cx = (1.0f / (1.0f + fexp(-bp[0])) + (float)wx) * inv;
            float cy = (1.0f / (1.0f + fexp(-bp[1])) + (float)hy) * inv;
            float bw = fexp(bp[2]) * anchors[2 * a]     * inv;
            float bh = fexp(bp[3]) * anchors[2 * a + 1] * inv;

            int pos = base_ + __popcll(mask & ((1ull << lane) - 1));
            if (pos < capacity) {
                pbox[pos]   = make_float4(cy - 0.5f * bh, cx - 0.5f * bw,
                                          cy + 0.5f * bh, cx + 0.5f * bw);
                pscore[pos] = score;
                pcls[pos]   = (float)am;
                pgi[pos]    = gi;
            }
        }
    }
}

// ---------------------------------------------------------------------------
// Rank + scatter + last-block batched walk.
// Phase A: scores+gi staged ONCE into LDS (coalesced), then each candidate's
//   rank is computed from wave-uniform broadcast ds_read_b128s with 4
//   independent accumulators (unroll 4 => >=8 LDS reads in flight). This
//   replaces round 18's serial L2-latency chain (~400ns/group -> ~25ns/group).
//   rank_i = #{j: s_j>s_i or (s_j==s_i && gi_j<gi_i)} — perfect permutation.
// Phase B (last block via ticket+fence, ONE wave): batched sorted walk,
//   kept-list in registers (static indices), == greedy NMS (round 18, passed).
// ---------------------------------------------------------------------------
__global__ __launch_bounds__(RANK_THREADS) void ranknms_kernel(
    const float4* __restrict__ pbox, const float* __restrict__ pscore,
    const float* __restrict__ pcls, const int* __restrict__ pgi,
    int* counters, int capacity,
    float4* __restrict__ sbox, float* __restrict__ ssc,
    float* __restrict__ scls, float* __restrict__ out)
{
    __shared__ __align__(16) float lsc[RANKCAP];
    __shared__ __align__(16) int   lgi[RANKCAP];
    __shared__ float orow[MAXOUT * 6];
    __shared__ int   lastFlag;

    const int tid = (int)threadIdx.x;
    const int gid = (int)blockIdx.x * RANK_THREADS + tid;

    int M = counters[0];
    if (M > capacity) M = capacity;

    // ---------------- phase A: rank + scatter ------------------------------
    if (M <= RANKCAP) {
        int Mr = (M + 3) & ~3;
        for (int j = tid; j < Mr; j += RANK_THREADS) {
            lsc[j] = (j < M) ? pscore[j] : -INFINITY;   // pad never counts
            lgi[j] = (j < M) ? pgi[j]    : 0x7fffffff;
        }
        __syncthreads();

        const float4* ls4 = reinterpret_cast<const float4*>(lsc);
        const int4*   lg4 = reinterpret_cast<const int4*>(lgi);
        const int groups = Mr >> 2;

        for (int i = gid; i < M; i += RANK_STRIDE) {
            float si  = lsc[i];
            int   gii = lgi[i];
            int r0 = 0, r1 = 0, r2 = 0, r3 = 0;   // independent chains
#pragma unroll 4
            for (int g = 0; g < groups; ++g) {
                float4 s4 = ls4[g];
                int4   g4 = lg4[g];
                r0 += (s4.x > si) || (s4.x == si && g4.x < gii);
                r1 += (s4.y > si) || (s4.y == si && g4.y < gii);
                r2 += (s4.z > si) || (s4.z == si && g4.z < gii);
                r3 += (s4.w > si) || (s4.w == si && g4.w < gii);
            }
            int rank = (r0 + r1) + (r2 + r3);
            sbox[rank] = pbox[i];
            ssc[rank]  = si;
            scls[rank] = pcls[i];
        }
    } else {
        // fallback: global-scan rank (M > 4096; never hit at M~1500)
        for (int i = gid; i < M; i += RANK_STRIDE) {
            float si  = pscore[i];
            int   gii = pgi[i];
            int rank = 0;
            for (int j = 0; j < M; ++j) {
                float sj = pscore[j];
                rank += (sj > si) || (sj == si && pgi[j] < gii);
            }
            sbox[rank] = pbox[i];
            ssc[rank]  = si;
            scls[rank] = pcls[i];
        }
    }

    // ---------------- ticket: last block proceeds --------------------------
    __syncthreads();
    if (tid == 0) {
        __threadfence();                       // publish sorted arrays
        int prev = atomicAdd(counters + 1, 1);
        lastFlag = (prev == (int)gridDim.x - 1);
    }
    __syncthreads();
    if (!lastFlag) return;
    __threadfence();                           // acquire all blocks' scatter

    // ---------------- phase B: batched walk (one wave) ---------------------
    if (tid < 64) {
        const int lane = tid;
        float4 kb[MAXOUT];                     // kept boxes (wave-uniform)
        int kept = 0;

        for (int r0b = 0; r0b < M && kept < MAXOUT; r0b += 64) {
            int r = r0b + lane;
            bool in = (r < M);
            float4 cb  = in ? sbox[r] : make_float4(0.f, 0.f, 0.f, 0.f);
            float  csc = in ? ssc[r]  : 0.f;
            float  ccl = in ? scls[r] : 0.f;
            float  ca  = fmaxf(cb.z - cb.x, 0.f) * fmaxf(cb.w - cb.y, 0.f);
            bool alive = in;

#pragma unroll
            for (int k = 0; k < MAXOUT; ++k) {
                if (k < kept && alive) {
                    float ka = fmaxf(kb[k].z - kb[k].x, 0.f)
                             * fmaxf(kb[k].w - kb[k].y, 0.f);
                    float ty = fmaxf(kb[k].x, cb.x);
                    float tx = fmaxf(kb[k].y, cb.y);
                    float by = fminf(kb[k].z, cb.z);
                    float bx = fminf(kb[k].w, cb.w);
                    float inter = fmaxf(by - ty, 0.f) * fmaxf(bx - tx, 0.f);
                    float iou = inter / (ka + ca - inter + 1e-9f);
                    if (iou > IOU_T) alive = false;
                }
            }

            unsigned long long am = __ballot(alive);
            while (am && kept < MAXOUT) {
                int w = (int)__ffsll((long long)am) - 1;   // lowest rank
                float wy0 = __shfl(cb.x, w), wx0 = __shfl(cb.y, w);
                float wy1 = __shfl(cb.z, w), wx1 = __shfl(cb.w, w);
                float wsc = __shfl(csc, w),  wcl = __shfl(ccl, w);

                if (lane == 0) {
                    orow[kept*6+0] = wy0; orow[kept*6+1] = wx0;
                    orow[kept*6+2] = wy1; orow[kept*6+3] = wx1;
                    orow[kept*6+4] = wsc; orow[kept*6+5] = wcl;
                }
#pragma unroll
                for (int k = 0; k < MAXOUT; ++k)   // kb[kept] via static idx
                    if (k == kept) kb[k] = make_float4(wy0, wx0, wy1, wx1);
                kept++;

                if (lane == w) alive = false;      // consumed
                if (alive) {                       // suppress vs new keep
                    float wa = fmaxf(wy1 - wy0, 0.f) * fmaxf(wx1 - wx0, 0.f);
                    float ty = fmaxf(wy0, cb.x);
                    float tx = fmaxf(wx0, cb.y);
                    float by = fminf(wy1, cb.z);
                    float bx = fminf(wx1, cb.w);
                    float inter = fmaxf(by - ty, 0.f) * fmaxf(bx - tx, 0.f);
                    float iou = inter / (wa + ca - inter + 1e-9f);
                    if (iou > IOU_T) alive = false;
                }
                am = __ballot(alive);
            }
        }

        if (lane == 0) {
            for (int it = kept; it < MAXOUT; ++it) {
                orow[it*6+0] = 0.f; orow[it*6+1] = 0.f; orow[it*6+2] = 0.f;
                orow[it*6+3] = 0.f; orow[it*6+4] = 0.f; orow[it*6+5] = 0.f;
            }
        }
    }

    __syncthreads();
    if (tid < MAXOUT * 6) out[tid] = orow[tid];   // single coalesced write
}

extern "C" void kernel_launch(void* const* d_in, const int* in_sizes, int n_in,
                              void* d_out, int out_size, void* d_ws, size_t ws_size,
                              hipStream_t stream) {
    (void)n_in; (void)out_size;
    const float* preds   = (const float*)d_in[0];
    const float* anchors = (const float*)d_in[1];
    float* out = (float*)d_out;

    int N = in_sizes[0] / CH;   // 216,320 boxes

    // Workspace: [0,64) counters; pbox f4[cap]; sbox f4[cap]; pscore, pcls,
    // ssc, scls (float[cap]); pgi (int[cap]). 52 B per slot, cap multiple
    // of 4 so every array stays 16B-aligned.
    char* ws = (char*)d_ws;
    int* counters = (int*)ws;
    size_t avail = (ws_size > 64) ? (ws_size - 64) : 0;
    long long cap = (long long)(avail / 52);
    if (cap > N) cap = N;
    if (cap < 0) cap = 0;
    cap &= ~3LL;
    int capacity = (int)cap;

    float4* pbox   = (float4*)(ws + 64);
    float4* sbox   = pbox + capacity;
    float*  pscore = (float*)(sbox + capacity);
    float*  pcls   = pscore + capacity;
    float*  ssc    = pcls + capacity;
    float*  scls   = ssc + capacity;
    int*    pgi    = (int*)(scls + capacity);

    init_counters_kernel<<<1, 1, 0, stream>>>(counters);

    int nBlocks = (N + WAVES_PB * BPW - 1) / (WAVES_PB * BPW);   // 1690
    decode_kernel<<<nBlocks, 256, 0, stream>>>(
        preds, anchors, pbox, pscore, pcls, pgi, counters, N, capacity);
    ranknms_kernel<<<RANK_BLOCKS, RANK_THREADS, 0, stream>>>(
        pbox, pscore, pcls, pgi, counters, capacity,
        sbox, ssc, scls, out);
}

// Round 20
// 67.119 us; speedup vs baseline: 2.9770x; 1.7489x over previous
//
#include <hip/hip_runtime.h>
#include <math.h>

#define A_N      5
#define GRID_HW  52
#define NCLS     80
#define CH       85
#define SCORE_T  0.15f
#define IOU_T    0.5f
#define MAXOUT   10

#define WAVES_PB     4                  // waves per decode block
#define BPW          32                 // boxes per wave
#define WAVE_FLOATS  (BPW * CH)         // 2720 floats = 10,880 B per wave
#define WAVE_FULL    10                 // 10 x 64 lanes x 16 B = 640 float4
#define WAVE_TAIL    40                 // +40 float4 = 680 = 2720 floats

#define RANK_BLOCKS  96
#define RANK_THREADS 256
#define CHUNK        512                // scores+gi per staged chunk (4 KB LDS)

// fast exp: v_exp_f32 (~1e-7 rel err). Argmax uses raw logits (exact); score
// values have 1.54 tolerance; proven across rounds 4-19 (absmax 0).
__device__ __forceinline__ float fexp(float x) { return __expf(x); }

// async global->LDS, 16B/lane. LDS dest = wave-uniform base + lane*16.
__device__ __forceinline__ void gload_lds16(const float* g, float* l) {
    __builtin_amdgcn_global_load_lds(
        (const __attribute__((address_space(1))) unsigned int*)g,
        (__attribute__((address_space(3))) unsigned int*)l, 16, 0, 0);
}

__global__ void init_counters_kernel(int* __restrict__ counters) {
    counters[0] = 0;   // compacted-slot counter
    counters[1] = 0;   // rank-kernel finished-block ticket
}

// ---------------------------------------------------------------------------
// Decode (unchanged logic): 4 independent waves/block, wave-local
// global_load_lds staging + vmcnt drain, 2 lanes/box one-pass softmax,
// ballot compaction. Writes pgi (argmax tie-break) and ZEROES prank[pos]
// so the rank kernel's atomic partials start from 0 every call.
// ---------------------------------------------------------------------------
__global__ __launch_bounds__(256) void decode_kernel(
    const float* __restrict__ preds,
    const float* __restrict__ anchors,
    float4* __restrict__ pbox, float* __restrict__ pscore,
    float* __restrict__ pcls, int* __restrict__ pgi,
    int* __restrict__ prank,
    int* __restrict__ counter, int N, int capacity)
{
    __shared__ __align__(16) float lds[WAVES_PB * WAVE_FLOATS];

    const int lane = (int)threadIdx.x & 63;
    const int wid  = (int)threadIdx.x >> 6;
    const int wt   = blockIdx.x * WAVES_PB + wid;   // wave-tile (32 boxes)
    if (wt * BPW >= N) return;                      // whole-wave guard

    const float* gbase = preds + (size_t)wt * WAVE_FLOATS;
    float* lbase = lds + wid * WAVE_FLOATS;

#pragma unroll
    for (int i = 0; i < WAVE_FULL; ++i)
        gload_lds16(gbase + (size_t)(i * 64 + lane) * 4, lbase + i * 256);
    if (lane < WAVE_TAIL)
        gload_lds16(gbase + (size_t)(WAVE_FULL * 64 + lane) * 4,
                    lbase + WAVE_FULL * 256);

    asm volatile("s_waitcnt vmcnt(0)" ::: "memory");
    __builtin_amdgcn_sched_barrier(0);

    const int b  = lane >> 1;            // box within wave segment (0..31)
    const int h  = lane & 1;             // half of the 80 classes
    const int gi = wt * BPW + b;
    const float* bp = lbase + b * CH;
    const float* cl = bp + 5 + h * 40;

    float s = 0.0f;
    float m = -INFINITY;
    int   am = h * 40;
#pragma unroll
    for (int j = 0; j < 40; ++j) {
        float x = cl[j];
        s += fexp(x);
        if (x > m) { m = x; am = h * 40 + j; }
    }
    {
        float m2 = __shfl_xor(m, 1);
        float s2 = __shfl_xor(s, 1);
        int   am2 = __shfl_xor(am, 1);
        s += s2;
        if (m2 > m || (m2 == m && am2 < am)) { m = m2; am = am2; }
    }

    float conf  = 1.0f / (1.0f + fexp(-bp[4]));
    float score = conf * fexp(m) / s;

    bool live = (h == 0) && (gi < N) && (score >= SCORE_T);

    unsigned long long mask = __ballot(live);
    if (mask) {
        int nlive  = __popcll(mask);
        int leader = (int)__ffsll((long long)mask) - 1;
        int base_ = 0;
        if (lane == leader) base_ = atomicAdd(counter, nlive);
        base_ = __shfl(base_, leader);
        if (live) {
            int a = gi % A_N;
            int t = gi / A_N;
            int wx = t % GRID_HW;
            int hy = (t / GRID_HW) % GRID_HW;
            const float inv = 1.0f / (float)GRID_HW;
            float cx = (1.0f / (1.0f + fexp(-bp[0])) + (float)wx) * inv;
            float cy = (1.0f / (1.0f + fexp(-bp[1])) + (float)hy) * inv;
            float bw = fexp(bp[2]) * anchors[2 * a]     * inv;
            float bh = fexp(bp[3]) * anchors[2 * a + 1] * inv;

            int pos = base_ + __popcll(mask & ((1ull << lane) - 1));
            if (pos < capacity) {
                pbox[pos]   = make_float4(cy - 0.5f * bh, cx - 0.5f * bw,
                                          cy + 0.5f * bh, cx + 0.5f * bw);
                pscore[pos] = score;
                pcls[pos]   = (float)am;
                pgi[pos]    = gi;
                prank[pos]  = 0;               // rank accumulator reset
            }
        }
    }
}

// ---------------------------------------------------------------------------
// Distributed rank + last-block scatter + batched walk.
// Phase A (all blocks, task-stride): task = (chunk c, candidate-group g).
//   Block stages chunk c's scores+gi into LDS (coalesced), then thread t
//   counts candidate i = g*256+t against the chunk (128 quad-groups, 4
//   independent accumulators) and atomicAdd's the partial into prank[i].
//   Exact, order-independent, deterministic. Per-thread chain: 128 groups
//   (vs round 19's 375 on 4x fewer waves — the measured latency wall).
// Phase B (last block via ticket+fence): scatter sbox[prank[i]] = pbox[i]
//   (perfect permutation: (score,gi) unique), then the batched sorted walk
//   (rounds 18/19, passed) — kept-list in registers, == greedy NMS.
// ---------------------------------------------------------------------------
__global__ __launch_bounds__(RANK_THREADS) void ranknms_kernel(
    const float4* __restrict__ pbox, const float* __restrict__ pscore,
    const float* __restrict__ pcls, const int* __restrict__ pgi,
    int* __restrict__ prank, int* counters, int capacity,
    float4* __restrict__ sbox, float* __restrict__ ssc,
    float* __restrict__ scls, float* __restrict__ out)
{
    __shared__ __align__(16) float lsc[CHUNK];
    __shared__ __align__(16) int   lgi[CHUNK];
    __shared__ float orow[MAXOUT * 6];
    __shared__ int   lastFlag;

    const int tid = (int)threadIdx.x;

    int M = counters[0];
    if (M > capacity) M = capacity;

    // ---------------- phase A: distributed rank ----------------------------
    const int nchunks = (M + CHUNK - 1) / CHUNK;
    const int ngroups = (M + RANK_THREADS - 1) / RANK_THREADS;
    const int ntasks  = nchunks * ngroups;

    for (int task = (int)blockIdx.x; task < ntasks; task += (int)gridDim.x) {
        const int c = task % nchunks;
        const int g = task / nchunks;
        const int cbase = c * CHUNK;
        const int csize = min(CHUNK, M - cbase);
        const int c4    = (csize + 3) & ~3;

        for (int k = tid; k < c4; k += RANK_THREADS) {
            lsc[k] = (k < csize) ? pscore[cbase + k] : -INFINITY; // pad: never counts
            lgi[k] = (k < csize) ? pgi[cbase + k]    : 0x7fffffff;
        }
        __syncthreads();

        const int i = g * RANK_THREADS + tid;
        if (i < M) {
            const float si  = pscore[i];
            const int   gii = pgi[i];
            const float4* ls4 = reinterpret_cast<const float4*>(lsc);
            const int4*   lg4 = reinterpret_cast<const int4*>(lgi);
            const int groups = c4 >> 2;
            int r0 = 0, r1 = 0, r2 = 0, r3 = 0;   // independent chains
#pragma unroll 4
            for (int q = 0; q < groups; ++q) {
                float4 s4 = ls4[q];
                int4   g4 = lg4[q];
                r0 += (s4.x > si) || (s4.x == si && g4.x < gii);
                r1 += (s4.y > si) || (s4.y == si && g4.y < gii);
                r2 += (s4.z > si) || (s4.z == si && g4.z < gii);
                r3 += (s4.w > si) || (s4.w == si && g4.w < gii);
            }
            atomicAdd(&prank[i], (r0 + r1) + (r2 + r3));
        }
        __syncthreads();   // protect lsc/lgi before next task's restage
    }

    // ---------------- ticket: last block proceeds --------------------------
    __syncthreads();
    if (tid == 0) {
        __threadfence();                       // publish partial ranks
        int prev = atomicAdd(counters + 1, 1);
        lastFlag = (prev == (int)gridDim.x - 1);
    }
    __syncthreads();
    if (!lastFlag) return;
    __threadfence();                           // acquire all blocks' atomics

    // ---------------- phase B: scatter + batched walk ----------------------
    for (int i = tid; i < M; i += RANK_THREADS) {
        int r = prank[i];
        sbox[r] = pbox[i];
        ssc[r]  = pscore[i];
        scls[r] = pcls[i];
    }
    __syncthreads();                           // sbox visible block-wide

    if (tid < 64) {
        const int lane = tid;
        float4 kb[MAXOUT];                     // kept boxes (wave-uniform)
        int kept = 0;

        for (int r0b = 0; r0b < M && kept < MAXOUT; r0b += 64) {
            int r = r0b + lane;
            bool in = (r < M);
            float4 cb  = in ? sbox[r] : make_float4(0.f, 0.f, 0.f, 0.f);
            float  csc = in ? ssc[r]  : 0.f;
            float  ccl = in ? scls[r] : 0.f;
            float  ca  = fmaxf(cb.z - cb.x, 0.f) * fmaxf(cb.w - cb.y, 0.f);
            bool alive = in;

#pragma unroll
            for (int k = 0; k < MAXOUT; ++k) {
                if (k < kept && alive) {
                    float ka = fmaxf(kb[k].z - kb[k].x, 0.f)
                             * fmaxf(kb[k].w - kb[k].y, 0.f);
                    float ty = fmaxf(kb[k].x, cb.x);
                    float tx = fmaxf(kb[k].y, cb.y);
                    float by = fminf(kb[k].z, cb.z);
                    float bx = fminf(kb[k].w, cb.w);
                    float inter = fmaxf(by - ty, 0.f) * fmaxf(bx - tx, 0.f);
                    float iou = inter / (ka + ca - inter + 1e-9f);
                    if (iou > IOU_T) alive = false;
                }
            }

            unsigned long long am = __ballot(alive);
            while (am && kept < MAXOUT) {
                int w = (int)__ffsll((long long)am) - 1;   // lowest rank
                float wy0 = __shfl(cb.x, w), wx0 = __shfl(cb.y, w);
                float wy1 = __shfl(cb.z, w), wx1 = __shfl(cb.w, w);
                float wsc = __shfl(csc, w),  wcl = __shfl(ccl, w);

                if (lane == 0) {
                    orow[kept*6+0] = wy0; orow[kept*6+1] = wx0;
                    orow[kept*6+2] = wy1; orow[kept*6+3] = wx1;
                    orow[kept*6+4] = wsc; orow[kept*6+5] = wcl;
                }
#pragma unroll
                for (int k = 0; k < MAXOUT; ++k)   // kb[kept] via static idx
                    if (k == kept) kb[k] = make_float4(wy0, wx0, wy1, wx1);
                kept++;

                if (lane == w) alive = false;      // consumed
                if (alive) {                       // suppress vs new keep
                    float wa = fmaxf(wy1 - wy0, 0.f) * fmaxf(wx1 - wx0, 0.f);
                    float ty = fmaxf(wy0, cb.x);
                    float tx = fmaxf(wx0, cb.y);
                    float by = fminf(wy1, cb.z);
                    float bx = fminf(wx1, cb.w);
                    float inter = fmaxf(by - ty, 0.f) * fmaxf(bx - tx, 0.f);
                    float iou = inter / (wa + ca - inter + 1e-9f);
                    if (iou > IOU_T) alive = false;
                }
                am = __ballot(alive);
            }
        }

        if (lane == 0) {
            for (int it = kept; it < MAXOUT; ++it) {
                orow[it*6+0] = 0.f; orow[it*6+1] = 0.f; orow[it*6+2] = 0.f;
                orow[it*6+3] = 0.f; orow[it*6+4] = 0.f; orow[it*6+5] = 0.f;
            }
        }
    }

    __syncthreads();
    if (tid < MAXOUT * 6) out[tid] = orow[tid];   // single coalesced write
}

extern "C" void kernel_launch(void* const* d_in, const int* in_sizes, int n_in,
                              void* d_out, int out_size, void* d_ws, size_t ws_size,
                              hipStream_t stream) {
    (void)n_in; (void)out_size;
    const float* preds   = (const float*)d_in[0];
    const float* anchors = (const float*)d_in[1];
    float* out = (float*)d_out;

    int N = in_sizes[0] / CH;   // 216,320 boxes

    // Workspace: [0,64) counters; pbox f4[cap]; sbox f4[cap]; pscore, pcls,
    // ssc, scls (float[cap]); pgi, prank (int[cap]). 56 B per slot, cap a
    // multiple of 4 so every array stays 16B-aligned.
    char* ws = (char*)d_ws;
    int* counters = (int*)ws;
    size_t avail = (ws_size > 64) ? (ws_size - 64) : 0;
    long long cap = (long long)(avail / 56);
    if (cap > N) cap = N;
    if (cap < 0) cap = 0;
    cap &= ~3LL;
    int capacity = (int)cap;

    float4* pbox   = (float4*)(ws + 64);
    float4* sbox   = pbox + capacity;
    float*  pscore = (float*)(sbox + capacity);
    float*  pcls   = pscore + capacity;
    float*  ssc    = pcls + capacity;
    float*  scls   = ssc + capacity;
    int*    pgi    = (int*)(scls + capacity);
    int*    prank  = pgi + capacity;

    init_counters_kernel<<<1, 1, 0, stream>>>(counters);

    int nBlocks = (N + WAVES_PB * BPW - 1) / (WAVES_PB * BPW);   // 1690
    decode_kernel<<<nBlocks, 256, 0, stream>>>(
        preds, anchors, pbox, pscore, pcls, pgi, prank, counters, N, capacity);
    ranknms_kernel<<<RANK_BLOCKS, RANK_THREADS, 0, stream>>>(
        pbox, pscore, pcls, pgi, prank, counters, capacity,
        sbox, ssc, scls, out);
}